// Round 2
// baseline (316.912 us; speedup 1.0000x reference)
//
#include <hip/hip_runtime.h>
#include <hip/hip_bf16.h>

// GrahamLoss: B=16, C=128, HW=16384, fp32 in, fp32[16] out.
// K1: split-K bf16-MFMA partial grams -> ws. K2: float4 sum + diff^2 partial. K3: final.
//
// v3: never-drain pipelined K1.
//  - global_load_lds (16B) stages fp32 directly into LDS: no staging VGPRs, no store phase.
//  - 4 LDS buffers x (128 rows x 32 f32) = 64 KB; 3-stage-deep prefetch; main loop waits
//    vmcnt(4) (counted, never 0); raw s_barrier (no implicit vmcnt(0)/lgkmcnt(0) drain).
//  - 512-thread blocks (8 waves, 64x32 tile each) -> 2 blocks/CU = 16 waves/CU.
//  - LDS XOR swizzle via pre-swizzled GLOBAL source (gload_lds writes linearly):
//    logical chunk cb stored at phys = cb ^ (r&7); read side applies the same XOR.
//  - bf16 conversion moved to fragment read (same f2bf bit math, same k order ->
//    bitwise-identical accumulation vs v2).

typedef __attribute__((ext_vector_type(8))) short short8;
typedef __attribute__((ext_vector_type(4))) float f32x4;

#define CC 128
#define NN 16384

// fp32 -> bf16 round-to-nearest-even (bit math; inputs are finite)
__device__ __forceinline__ short f2bf(float x) {
    unsigned u = __builtin_bit_cast(unsigned, x);
    u += 0x7fffu + ((u >> 16) & 1u);
    return (short)(u >> 16);
}

#define WAITV(N) asm volatile("s_waitcnt vmcnt(" #N ")" ::: "memory")
#define BAR() do { __builtin_amdgcn_s_barrier(); __builtin_amdgcn_sched_barrier(0); } while (0)

__global__ __launch_bounds__(512, 4) void gram_partial_k(
    const float* __restrict__ f0, const float* __restrict__ f1,
    float* __restrict__ partials, int S, int Kc, int nst)
{
    // 4 buffers, each one k32 stage: 128 rows x 32 f32 (row = 128 B = 8 x 16B chunks)
    __shared__ float lds_f[4 * 128 * 32];   // 64 KB

    const int tid = threadIdx.x;
    const int bx  = blockIdx.x;
    const int g   = bx & 31;   // gram id: batch*2 + src
    const int s   = bx >> 5;   // k-chunk

    const float* src  = (g & 1) ? f1 : f0;
    const float* base = src + (size_t)(g >> 1) * ((size_t)CC * NN) + (size_t)s * Kc;

    const int lane = tid & 63;
    const int w    = tid >> 6;          // wave id 0..7
    const int m0   = (w & 1) * 64;
    const int n0   = ((w >> 1) & 3) * 32;
    const int lr   = lane & 15;
    const int lk   = lane >> 4;

    // staging: 2 gload_lds per thread per stage. Instr i covers rows i*64 + w*8 + lane/8,
    // 16B chunk (lane&7). Source pre-swizzled so linear LDS write = swizzled layout.
    const int r0  = 0 * 64 + w * 8 + (lane >> 3);
    const int r1  = 1 * 64 + w * 8 + (lane >> 3);
    const int cb0 = (lane & 7) ^ (r0 & 7);
    const int cb1 = (lane & 7) ^ (r1 & 7);
    const float* gb0 = base + (size_t)r0 * NN + cb0 * 4;
    const float* gb1 = base + (size_t)r1 * NN + cb1 * 4;

    auto issue_stage = [&](int st) {
        int buf = st & 3;
        const float* g0 = gb0 + (size_t)st * 32;
        const float* g1 = gb1 + (size_t)st * 32;
        __builtin_amdgcn_global_load_lds(
            (const __attribute__((address_space(1))) void*)g0,
            (__attribute__((address_space(3))) void*)&lds_f[buf * 4096 + 0 * 2048 + w * 256],
            16, 0, 0);
        __builtin_amdgcn_global_load_lds(
            (const __attribute__((address_space(1))) void*)g1,
            (__attribute__((address_space(3))) void*)&lds_f[buf * 4096 + 1 * 2048 + w * 256],
            16, 0, 0);
    };

    f32x4 acc[4][2];
    #pragma unroll
    for (int i = 0; i < 4; ++i)
        #pragma unroll
        for (int j = 0; j < 2; ++j)
            acc[i][j] = (f32x4){0.f, 0.f, 0.f, 0.f};

    auto compute = [&](int st) {
        int buf = st & 3;
        const float* lb = &lds_f[buf * 4096];
        short8 af[4], bf2[2];
        #pragma unroll
        for (int i = 0; i < 4; ++i) {
            int row = m0 + i * 16 + lr;
            int c0  = (lk * 2)     ^ (row & 7);
            int c1  = (lk * 2 + 1) ^ (row & 7);
            float4 x0 = *(const float4*)&lb[row * 32 + c0 * 4];
            float4 x1 = *(const float4*)&lb[row * 32 + c1 * 4];
            af[i] = (short8){ f2bf(x0.x), f2bf(x0.y), f2bf(x0.z), f2bf(x0.w),
                              f2bf(x1.x), f2bf(x1.y), f2bf(x1.z), f2bf(x1.w) };
        }
        #pragma unroll
        for (int j2 = 0; j2 < 2; ++j2) {
            int row = n0 + j2 * 16 + lr;
            int c0  = (lk * 2)     ^ (row & 7);
            int c1  = (lk * 2 + 1) ^ (row & 7);
            float4 x0 = *(const float4*)&lb[row * 32 + c0 * 4];
            float4 x1 = *(const float4*)&lb[row * 32 + c1 * 4];
            bf2[j2] = (short8){ f2bf(x0.x), f2bf(x0.y), f2bf(x0.z), f2bf(x0.w),
                                f2bf(x1.x), f2bf(x1.y), f2bf(x1.z), f2bf(x1.w) };
        }
        #pragma unroll
        for (int mi = 0; mi < 4; ++mi)
            #pragma unroll
            for (int ni = 0; ni < 2; ++ni)
                acc[mi][ni] = __builtin_amdgcn_mfma_f32_16x16x32_bf16(
                    af[mi], bf2[ni], acc[mi][ni], 0, 0, 0);
    };

    // prologue: 3 stages in flight; drain stage 0 only (4 loads still outstanding)
    issue_stage(0);
    issue_stage(1);
    issue_stage(2);
    WAITV(4);
    BAR();

    // main loop: issue 3 ahead, wait counted vmcnt(4) -> stage j+1 landed, j+2/j+3 in flight
    for (int j = 0; j < nst - 3; ++j) {
        issue_stage(j + 3);
        compute(j);
        WAITV(4);
        BAR();
    }
    compute(nst - 3); WAITV(2); BAR();
    compute(nst - 2); WAITV(0); BAR();
    compute(nst - 1);

    // epilogue: write partial gram (consistent bijective lane->slot map)
    float* op = partials + ((size_t)g * S + s) * (CC * CC);
    #pragma unroll
    for (int mi = 0; mi < 4; ++mi)
        #pragma unroll
        for (int ni = 0; ni < 2; ++ni)
            #pragma unroll
            for (int i = 0; i < 4; ++i) {
                int row = m0 + mi * 16 + lk * 4 + i;
                int col = n0 + ni * 16 + lr;
                op[row * CC + col] = acc[mi][ni][i];
            }
}

__global__ __launch_bounds__(256) void reduce1_k(
    const float* __restrict__ partials, float* __restrict__ part2, int S)
{
    int b     = blockIdx.x >> 4;   // batch
    int chunk = blockIdx.x & 15;   // 1024-entry chunk of the 16384-entry gram
    int t     = threadIdx.x;
    size_t e  = (size_t)chunk * 1024 + (size_t)t * 4;

    const f32x4* Pe = (const f32x4*)(partials + ((size_t)(2 * b) * S) * (CC * CC) + e);
    const f32x4* Pd = (const f32x4*)(partials + ((size_t)(2 * b + 1) * S) * (CC * CC) + e);
    const size_t stride = (size_t)CC * CC / 4;

    f32x4 ae = {0.f, 0.f, 0.f, 0.f}, ad = {0.f, 0.f, 0.f, 0.f};
    if (S == 16) {
        #pragma unroll
        for (int s2 = 0; s2 < 16; ++s2) {
            ae += Pe[(size_t)s2 * stride];
            ad += Pd[(size_t)s2 * stride];
        }
    } else {
        for (int s2 = 0; s2 < S; ++s2) {
            ae += Pe[(size_t)s2 * stride];
            ad += Pd[(size_t)s2 * stride];
        }
    }
    f32x4 d = ad - ae;
    float v = d[0] * d[0] + d[1] * d[1] + d[2] * d[2] + d[3] * d[3];
    #pragma unroll
    for (int off = 32; off > 0; off >>= 1) v += __shfl_down(v, off);
    __shared__ float wsum[4];
    if ((t & 63) == 0) wsum[t >> 6] = v;
    __syncthreads();
    if (t == 0) part2[b * 16 + chunk] = wsum[0] + wsum[1] + wsum[2] + wsum[3];
}

__global__ void reduce2_k(const float* __restrict__ part2, float* __restrict__ out)
{
    int b = blockIdx.x;
    int t = threadIdx.x;  // 64
    float v = (t < 16) ? part2[b * 16 + t] : 0.f;
    #pragma unroll
    for (int off = 8; off > 0; off >>= 1) v += __shfl_down(v, off);
    // denom = 4 * (HW)^2 * C^2 = 2^44 exactly
    if (t == 0) out[b] = v * (1.0f / 17592186044416.0f);
}

extern "C" void kernel_launch(void* const* d_in, const int* in_sizes, int n_in,
                              void* d_out, int out_size, void* d_ws, size_t ws_size,
                              hipStream_t stream)
{
    const float* f0 = (const float*)d_in[0];  // feat
    const float* f1 = (const float*)d_in[1];  // feat_decod
    float* out = (float*)d_out;

    // adaptive split-K: S power of 2 <= 16 such that partials fit in ws
    const size_t perS = 32ull * CC * CC * 4;  // 2 MiB per k-chunk unit (32 grams)
    const size_t tail = 16 * 16 * 4;
    int S = 16;
    while (S > 1 && perS * (size_t)S + tail > ws_size) S >>= 1;
    int Kc  = NN / S;
    int nst = Kc / 32;   // one k32 stage per buffer

    float* partials = (float*)d_ws;
    float* part2    = (float*)((char*)d_ws + perS * (size_t)S);

    gram_partial_k<<<32 * S, 512, 0, stream>>>(f0, f1, partials, S, Kc, nst);
    reduce1_k<<<16 * 16, 256, 0, stream>>>(partials, part2, S);
    reduce2_k<<<16, 64, 0, stream>>>(part2, out);
}

// Round 3
// 299.095 us; speedup vs baseline: 1.0596x; 1.0596x over previous
//
#include <hip/hip_runtime.h>
#include <hip/hip_bf16.h>

// GrahamLoss: B=16, C=128, HW=16384, fp32 in, fp32[16] out.
// K1: split-K bf16-MFMA partial grams -> ws. K2: float4 sum + diff^2 partial. K3: final.
//
// v4: occupancy fix. v1/v2/v3 all ran 512 blocks = 2 blocks/CU (18% occupancy),
// latency-bound with both pipes idle. This version returns to the proven v1
// structure (reg-staged, double-buffered 32KB LDS, 64-col stages) and doubles
// split-K: S=32 -> 1024 blocks -> 4 blocks/CU resident (LDS and VGPR both allow it).
// Stage-order rotation kept (decorrelates column windows across blocks).

typedef __attribute__((ext_vector_type(8))) short short8;
typedef __attribute__((ext_vector_type(4))) float f32x4;

#define CC 128
#define NN 16384

// fp32 -> bf16 round-to-nearest-even (bit math; inputs are finite)
__device__ __forceinline__ short f2bf(float x) {
    unsigned u = __builtin_bit_cast(unsigned, x);
    u += 0x7fffu + ((u >> 16) & 1u);
    return (short)(u >> 16);
}

__global__ __launch_bounds__(256, 4) void gram_partial_k(
    const float* __restrict__ f0, const float* __restrict__ f1,
    float* __restrict__ partials, int S, int Kc, int nst)
{
    // LDS: double buffer, 128 rows x 64 bf16, swizzled in 16B blocks: phys = cb ^ (r&7)
    __shared__ short lds[2][CC * 64];   // 32 KB

    const int tid = threadIdx.x;
    const int bx  = blockIdx.x;
    const int g   = bx & 31;   // gram id: batch*2 + src
    const int s   = bx >> 5;   // k-chunk

    const float* src  = (g & 1) ? f1 : f0;
    const float* base = src + (size_t)(g >> 1) * ((size_t)CC * NN) + (size_t)s * Kc;

    // staging map: 8 threads per row (8 consecutive f32 each), 32 rows per sweep
    const int srow = tid >> 3;   // 0..31
    const int scb  = tid & 7;    // 16B-block index within 64-col stage
    const float* gp = base + (size_t)srow * NN + scb * 8;

    const int lane = tid & 63;
    const int w    = tid >> 6;
    const int m0   = (w & 1) * 64;
    const int n0   = (w >> 1) * 64;
    const int lr   = lane & 15;
    const int lk   = lane >> 4;

    // stage-order rotation phase (k-sum commutes; decorrelates column windows)
    const int rot = bx & (nst - 1);

    f32x4 acc[4][4];
    #pragma unroll
    for (int i = 0; i < 4; ++i)
        #pragma unroll
        for (int j = 0; j < 4; ++j)
            acc[i][j] = (f32x4){0.f, 0.f, 0.f, 0.f};

    float4 ra[4], rb[4];

    auto load_stage = [&](int st) {
        int sp = (st + rot) & (nst - 1);
        #pragma unroll
        for (int it = 0; it < 4; ++it) {
            const float* p = gp + (size_t)it * 32 * NN + (size_t)sp * 64;
            ra[it] = *(const float4*)p;
            rb[it] = *(const float4*)(p + 4);
        }
    };

    auto store_stage = [&](int buf) {
        #pragma unroll
        for (int it = 0; it < 4; ++it) {
            int r = srow + 32 * it;
            short8 v = { f2bf(ra[it].x), f2bf(ra[it].y), f2bf(ra[it].z), f2bf(ra[it].w),
                         f2bf(rb[it].x), f2bf(rb[it].y), f2bf(rb[it].z), f2bf(rb[it].w) };
            int phys = scb ^ (r & 7);
            *(short8*)&lds[buf][r * 64 + phys * 8] = v;
        }
    };

    auto compute = [&](int buf) {
        #pragma unroll
        for (int ks = 0; ks < 2; ++ks) {
            short8 af[4], bfr[4];
            int cb = ks * 4 + lk;
            #pragma unroll
            for (int i = 0; i < 4; ++i) {
                int r = m0 + i * 16 + lr;
                af[i] = *(const short8*)&lds[buf][r * 64 + ((cb ^ (r & 7)) * 8)];
            }
            #pragma unroll
            for (int i = 0; i < 4; ++i) {
                int r = n0 + i * 16 + lr;
                bfr[i] = *(const short8*)&lds[buf][r * 64 + ((cb ^ (r & 7)) * 8)];
            }
            #pragma unroll
            for (int mi = 0; mi < 4; ++mi)
                #pragma unroll
                for (int ni = 0; ni < 4; ++ni)
                    acc[mi][ni] = __builtin_amdgcn_mfma_f32_16x16x32_bf16(
                        af[mi], bfr[ni], acc[mi][ni], 0, 0, 0);
        }
    };

    load_stage(0);
    store_stage(0);
    __syncthreads();
    for (int st = 0; st < nst; ++st) {
        int cur = st & 1;
        bool more = (st + 1 < nst);
        if (more) load_stage(st + 1);
        compute(cur);
        if (more) store_stage(cur ^ 1);
        __syncthreads();
    }

    // epilogue: write partial gram (any consistent bijective lane->slot map is OK)
    float* op = partials + ((size_t)g * S + s) * (CC * CC);
    #pragma unroll
    for (int mi = 0; mi < 4; ++mi)
        #pragma unroll
        for (int ni = 0; ni < 4; ++ni)
            #pragma unroll
            for (int i = 0; i < 4; ++i) {
                int row = m0 + mi * 16 + lk * 4 + i;
                int col = n0 + ni * 16 + lr;
                op[row * CC + col] = acc[mi][ni][i];
            }
}

__global__ __launch_bounds__(256) void reduce1_k(
    const float* __restrict__ partials, float* __restrict__ part2, int S)
{
    int b     = blockIdx.x >> 4;   // batch
    int chunk = blockIdx.x & 15;   // 1024-entry chunk of the 16384-entry gram
    int t     = threadIdx.x;
    size_t e  = (size_t)chunk * 1024 + (size_t)t * 4;

    const f32x4* Pe = (const f32x4*)(partials + ((size_t)(2 * b) * S) * (CC * CC) + e);
    const f32x4* Pd = (const f32x4*)(partials + ((size_t)(2 * b + 1) * S) * (CC * CC) + e);
    const size_t stride = (size_t)CC * CC / 4;

    f32x4 ae = {0.f, 0.f, 0.f, 0.f}, ad = {0.f, 0.f, 0.f, 0.f};
    #pragma unroll 8
    for (int s2 = 0; s2 < S; ++s2) {
        ae += Pe[(size_t)s2 * stride];
        ad += Pd[(size_t)s2 * stride];
    }
    f32x4 d = ad - ae;
    float v = d[0] * d[0] + d[1] * d[1] + d[2] * d[2] + d[3] * d[3];
    #pragma unroll
    for (int off = 32; off > 0; off >>= 1) v += __shfl_down(v, off);
    __shared__ float wsum[4];
    if ((t & 63) == 0) wsum[t >> 6] = v;
    __syncthreads();
    if (t == 0) part2[b * 16 + chunk] = wsum[0] + wsum[1] + wsum[2] + wsum[3];
}

__global__ void reduce2_k(const float* __restrict__ part2, float* __restrict__ out)
{
    int b = blockIdx.x;
    int t = threadIdx.x;  // 64
    float v = (t < 16) ? part2[b * 16 + t] : 0.f;
    #pragma unroll
    for (int off = 8; off > 0; off >>= 1) v += __shfl_down(v, off);
    // denom = 4 * (HW)^2 * C^2 = 2^44 exactly
    if (t == 0) out[b] = v * (1.0f / 17592186044416.0f);
}

extern "C" void kernel_launch(void* const* d_in, const int* in_sizes, int n_in,
                              void* d_out, int out_size, void* d_ws, size_t ws_size,
                              hipStream_t stream)
{
    const float* f0 = (const float*)d_in[0];  // feat
    const float* f1 = (const float*)d_in[1];  // feat_decod
    float* out = (float*)d_out;

    // adaptive split-K: S power of 2 <= 32 such that partials fit in ws
    const size_t perS = 32ull * CC * CC * 4;  // 2 MiB per k-chunk unit (32 grams)
    const size_t tail = 16 * 16 * 4;
    int S = 32;
    while (S > 1 && perS * (size_t)S + tail > ws_size) S >>= 1;
    int Kc  = NN / S;
    int nst = Kc / 64;

    float* partials = (float*)d_ws;
    float* part2    = (float*)((char*)d_ws + perS * (size_t)S);

    gram_partial_k<<<32 * S, 256, 0, stream>>>(f0, f1, partials, S, Kc, nst);
    reduce1_k<<<16 * 16, 256, 0, stream>>>(partials, part2, S);
    reduce2_k<<<16, 64, 0, stream>>>(part2, out);
}